// Round 1
// 449.039 us; speedup vs baseline: 1.0054x; 1.0054x over previous
//
#include <hip/hip_runtime.h>
#include <hip/hip_bf16.h>
#include <math.h>

#define Bn   16
#define Jn   2048
#define Hn   2048
#define OUTn 128
#define HDn  16

// proj tiling: block M=64 (j), N=160 (128 q + 16 v + 1 ksum + 15 zero), KC=64
#define KC      64
#define NCHUNK  (Hn / KC)          // 32
#define B_UNITS 1280               // 160*64/8 units of 8 bf16 per plane
#define WPK_CHUNK_BYTES (2 * B_UNITS * 16)   // 40960 B per chunk (hi+lo)

// workspace layout (floats)
#define WS_PART1 2048                        // [256][2048] col-sum partials
#define WS_WPK   (WS_PART1 + 256 * 2048)     // packed weights (uint4 region)
#define WS_PART  (WS_WPK + NCHUNK * 2 * B_UNITS * 4)  // [16][32][128][17] attn partials

typedef __attribute__((ext_vector_type(8))) short bf16x8_t;
typedef __attribute__((ext_vector_type(4))) float f32x4_t;

typedef __attribute__((address_space(1))) const void gvoid_t;
typedef __attribute__((address_space(3))) void lvoid_t;

__device__ __forceinline__ unsigned short f2bf(float x) {
  unsigned u = __builtin_bit_cast(unsigned, x);
  unsigned r = (u + 0x7fffu + ((u >> 16) & 1u)) >> 16;
  return (unsigned short)r;
}
__device__ __forceinline__ float bf2f(unsigned short h) {
  unsigned u = ((unsigned)h) << 16;
  return __builtin_bit_cast(float, u);
}

// convert 8 consecutive fp32 -> split-bf16 (hi + lo) fragments, bitwise
// identical to the old LDS-staging conversion
__device__ __forceinline__ void cvt8(const float4 u, const float4 v,
                                     bf16x8_t& h, bf16x8_t& l) {
  float x[8] = {u.x, u.y, u.z, u.w, v.x, v.y, v.z, v.w};
#pragma unroll
  for (int i = 0; i < 8; ++i) {
    const unsigned short hi = f2bf(x[i]);
    h[i] = (short)hi;
    l[i] = (short)f2bf(x[i] - bf2f(hi));
  }
}

// -------- prep1: contention-free column-sum partials of wk_w ---------------
__global__ __launch_bounds__(256) void prep1_kernel(const float* __restrict__ wk_w,
                                                    const float* __restrict__ wk_b,
                                                    float* __restrict__ ws) {
  const int blk = blockIdx.x;
  const int tid = threadIdx.x;
  if (blk < 256) {
    const int h0 = blk * 8;
    const int c0 = tid * 8;
    float a[8] = {0.f, 0.f, 0.f, 0.f, 0.f, 0.f, 0.f, 0.f};
#pragma unroll
    for (int h = 0; h < 8; ++h) {
      const float* row = wk_w + (size_t)(h0 + h) * Hn + c0;
      const float4 u = *(const float4*)row;
      const float4 v = *(const float4*)(row + 4);
      a[0] += u.x; a[1] += u.y; a[2] += u.z; a[3] += u.w;
      a[4] += v.x; a[5] += v.y; a[6] += v.z; a[7] += v.w;
    }
    float* dst = ws + WS_PART1 + (size_t)blk * Hn + c0;
    *(float4*)dst       = make_float4(a[0], a[1], a[2], a[3]);
    *(float4*)(dst + 4) = make_float4(a[4], a[5], a[6], a[7]);
  } else {
    __shared__ float red[256];
    float s = 0.f;
    for (int h = tid; h < Hn; h += 256) s += wk_b[h];
    red[tid] = s;
    __syncthreads();
    for (int off = 128; off > 0; off >>= 1) {
      if (tid < off) red[tid] += red[tid + off];
      __syncthreads();
    }
    if (tid == 0) ws[0] = red[0];
  }
}

// -------- prep2: pack weights into split-bf16, MFMA-tile-linear stream ------
__global__ __launch_bounds__(256) void prep2_kernel(const float* __restrict__ wq_w,
                                                    const float* __restrict__ wv_w,
                                                    const float* __restrict__ ws,
                                                    uint4* __restrict__ wpk) {
  const int id = blockIdx.x * 256 + threadIdx.x;     // 0 .. 40959
  const int chunk = id / B_UNITS;
  const int u     = id % B_UNITS;
  const int kblk  = u / 640;
  const int u2    = u % 640;
  const int nt    = u2 >> 6;
  const int g     = (u2 >> 4) & 3;
  const int n16   = u2 & 15;
  const int n     = nt * 16 + n16;
  const int k     = chunk * KC + kblk * 32 + g * 8;

  float x[8];
  if (n < OUTn) {
    const float* s = wq_w + (size_t)n * Hn + k;
#pragma unroll
    for (int i = 0; i < 8; ++i) x[i] = s[i];
  } else if (n < OUTn + HDn) {
    const float* s = wv_w + (size_t)(n - OUTn) * Hn + k;
#pragma unroll
    for (int i = 0; i < 8; ++i) x[i] = s[i];
  } else if (n == OUTn + HDn) {
#pragma unroll
    for (int i = 0; i < 8; ++i) x[i] = 0.f;
    const float* p1 = ws + WS_PART1 + k;
    // unroll 8: batch the independent loads so latency overlaps (same fp
    // accumulation order per x[i] -> bitwise identical result)
#pragma unroll 8
    for (int p = 0; p < 256; ++p) {
      const float4 a = *(const float4*)p1;
      const float4 b = *(const float4*)(p1 + 4);
      x[0] += a.x; x[1] += a.y; x[2] += a.z; x[3] += a.w;
      x[4] += b.x; x[5] += b.y; x[6] += b.z; x[7] += b.w;
      p1 += Hn;
    }
  } else {
#pragma unroll
    for (int i = 0; i < 8; ++i) x[i] = 0.f;
  }

  unsigned short hi[8], lo[8];
#pragma unroll
  for (int i = 0; i < 8; ++i) {
    hi[i] = f2bf(x[i]);
    lo[i] = f2bf(x[i] - bf2f(hi[i]));
  }
  uint4 uh, ul;
  uh.x = (unsigned)hi[0] | ((unsigned)hi[1] << 16);
  uh.y = (unsigned)hi[2] | ((unsigned)hi[3] << 16);
  uh.z = (unsigned)hi[4] | ((unsigned)hi[5] << 16);
  uh.w = (unsigned)hi[6] | ((unsigned)hi[7] << 16);
  ul.x = (unsigned)lo[0] | ((unsigned)lo[1] << 16);
  ul.y = (unsigned)lo[2] | ((unsigned)lo[3] << 16);
  ul.z = (unsigned)lo[4] | ((unsigned)lo[5] << 16);
  ul.w = (unsigned)lo[6] | ((unsigned)lo[7] << 16);
  wpk[(size_t)(chunk * 2 + 0) * B_UNITS + u] = uh;
  wpk[(size_t)(chunk * 2 + 1) * B_UNITS + u] = ul;
}

// -------- proj: 1-barrier-per-chunk pipelined split-bf16 MFMA GEMM ----------
// Structure (T3-lite 2-phase template):
//  - each wave owns ONE 16-row m-tile; A fragments load global->reg directly
//    (lane holds row lane&15, k-slice (lane>>4)*8 -- exactly the mfma
//    16x16x32 A layout), prefetched one chunk ahead.
//  - B double-buffered in LDS (2 x 40 KB), staged one chunk ahead via
//    global_load_lds.
//  - per chunk: one s_waitcnt vmcnt(4) (drains the 10 B stages; leaves the
//    4 A-prefetch loads in flight -- B issued before A, vmcnt retires in
//    order) + one raw s_barrier.
// Numerics: identical MFMA chains and identical epilogue summation tree as
// the previous kernel (q accs spilled to LDS, old epilogue verbatim).
__global__ __launch_bounds__(256, 2) void proj_kernel(
    const float* __restrict__ vec,
    const float* __restrict__ wq_b,
    const float* __restrict__ wv_b,
    const float* __restrict__ wsc,     // ws[0] = wkb sum
    const uint4* __restrict__ wpk,     // packed split-bf16 weights
    float* __restrict__ part)          // [B][32][128][17] attn partials
{
  __shared__ uint4 Bs[2][2 * B_UNITS];   // 2 x 40 KB double-buffered B

  const int tid   = threadIdx.x;
  const int lane  = tid & 63;
  const int w     = tid >> 6;          // wave 0..3 = m-tile index
  const int b     = blockIdx.x >> 5;
  const int jt    = blockIdx.x & 31;
  const int j0    = jt * 64;
  const int col16 = lane & 15;
  const int rbase = (lane >> 4) * 4;

  // per-lane A base: row (w*16 + lane&15), k-offset (lane>>4)*8
  const float* aptr = vec + (size_t)b * Jn * Hn
                    + (size_t)(j0 + w * 16 + col16) * Hn + (lane >> 4) * 8;

  f32x4_t acc[10];
#pragma unroll
  for (int ni = 0; ni < 10; ++ni) acc[ni] = (f32x4_t){0.f, 0.f, 0.f, 0.f};

#define STAGE_B(ch_, buf_)                                                    \
  do {                                                                        \
    const char* gb_ = (const char*)wpk + (size_t)(ch_) * WPK_CHUNK_BYTES +    \
                      (size_t)lane * 16;                                      \
    uint4* bd_ = &Bs[buf_][0];                                                \
    _Pragma("unroll")                                                         \
    for (int i_ = 0; i_ < 10; ++i_) {                                         \
      const int q_ = w + i_ * 4;                                              \
      __builtin_amdgcn_global_load_lds((gvoid_t*)(gb_ + q_ * 1024),           \
                                       (lvoid_t*)(bd_ + q_ * 64), 16, 0, 0);  \
    }                                                                         \
  } while (0)

// one K-chunk: stage B(ch+1) -> other buffer, prefetch A(ch+1) -> regs,
// convert current A regs, 60 MFMAs from Bs[buf_], counted wait + barrier.
#define CHUNK_BODY(ch_, buf_, u0, u1, u2, u3, v0_, v1_, v2_, v3_)             \
  do {                                                                        \
    if ((ch_) + 1 < NCHUNK) { STAGE_B((ch_) + 1, (buf_) ^ 1); }               \
    asm volatile("" ::: "memory"); /* order: B stages before A prefetch */    \
    if ((ch_) + 1 < NCHUNK) {                                                 \
      const float* ap_ = aptr + (size_t)((ch_) + 1) * KC;                     \
      v0_ = *(const float4*)(ap_);                                            \
      v1_ = *(const float4*)(ap_ + 4);                                        \
      v2_ = *(const float4*)(ap_ + 32);                                       \
      v3_ = *(const float4*)(ap_ + 36);                                       \
    }                                                                         \
    bf16x8_t ah0_, al0_, ah1_, al1_;                                          \
    cvt8(u0, u1, ah0_, al0_);                                                 \
    cvt8(u2, u3, ah1_, al1_);                                                 \
    const bf16x8_t* B8_ = (const bf16x8_t*)&Bs[buf_][0];                      \
    _Pragma("unroll")                                                         \
    for (int kb_ = 0; kb_ < 2; ++kb_) {                                       \
      const bf16x8_t ah_ = kb_ ? ah1_ : ah0_;                                 \
      const bf16x8_t al_ = kb_ ? al1_ : al0_;                                 \
      _Pragma("unroll")                                                       \
      for (int ni_ = 0; ni_ < 10; ++ni_) {                                    \
        const int idx_ = (kb_ * 10 + ni_) * 64 + lane;                        \
        const bf16x8_t bh_ = B8_[idx_];                                       \
        const bf16x8_t bl_ = B8_[B_UNITS + idx_];                             \
        acc[ni_] = __builtin_amdgcn_mfma_f32_16x16x32_bf16(ah_, bh_, acc[ni_], 0, 0, 0); \
        acc[ni_] = __builtin_amdgcn_mfma_f32_16x16x32_bf16(ah_, bl_, acc[ni_], 0, 0, 0); \
        acc[ni_] = __builtin_amdgcn_mfma_f32_16x16x32_bf16(al_, bh_, acc[ni_], 0, 0, 0); \
      }                                                                       \
    }                                                                         \
    asm volatile("s_waitcnt vmcnt(4)" ::: "memory"); /* B staged; A flying */ \
    __builtin_amdgcn_s_barrier();                                             \
  } while (0)

  // prologue: stage B(0), load A(0)
  STAGE_B(0, 0);
  asm volatile("" ::: "memory");
  float4 c0 = *(const float4*)(aptr);
  float4 c1 = *(const float4*)(aptr + 4);
  float4 c2 = *(const float4*)(aptr + 32);
  float4 c3 = *(const float4*)(aptr + 36);
  asm volatile("s_waitcnt vmcnt(4)" ::: "memory");
  __builtin_amdgcn_s_barrier();

  float4 n0, n1, n2, n3;
  for (int ch = 0; ch < NCHUNK; ch += 2) {
    CHUNK_BODY(ch,     0, c0, c1, c2, c3, n0, n1, n2, n3);
    CHUNK_BODY(ch + 1, 1, n0, n1, n2, n3, c0, c1, c2, c3);
  }
#undef CHUNK_BODY
#undef STAGE_B

  // ==== fused attention epilogue (bitwise identical to previous kernel) ====
  // C/D layout: col=lane&15, row=(lane>>4)*4+reg.
  // LDS reuse: q_lds[64][132] + ks[64] + vt[64][20] + epi[2][128][18]
  const float wkb = wsc[0];
  float* q_lds = (float*)Bs;               // 8448 floats
  float* ks_s  = q_lds + 64 * 132;         // [64]
  float* vt    = ks_s + 64;                // [64][20], rows 16B-aligned
  float* epi   = vt + 64 * 20;             // [2][128][18]

  {
    // spill q accs (ni 0..7 -> i = ni*16+col16) for this wave's 16 rows
#pragma unroll
    for (int ni = 0; ni < 8; ++ni) {
#pragma unroll
      for (int r = 0; r < 4; ++r) {
        q_lds[(size_t)(w * 16 + rbase + r) * 132 + ni * 16 + col16] = acc[ni][r];
      }
    }
    const float vb_ = wv_b[col16];
#pragma unroll
    for (int r = 0; r < 4; ++r) {
      const int jj = w * 16 + rbase + r;
      vt[jj * 20 + col16] = acc[8][r] + vb_;   // v columns: n = 128 + col16
    }
    if (col16 == 0) {
#pragma unroll
      for (int r = 0; r < 4; ++r) {
        const int jj = w * 16 + rbase + r;
        ks_s[jj] = acc[9][r] + wkb;            // ksum column: n = 144
      }
    }
  }
  __syncthreads();

  // old epilogue verbatim (wm/wn wave roles), q sourced from q_lds
  const int wm   = w >> 1;
  const int wn   = w & 1;
  const int NCOL = wn ? 3 : 5;           // q columns this wave owns (uniform)
  float* epiw = epi + wm * 128 * 18;     // this wave's disjoint slab

#pragma unroll 5
  for (int ni = 0; ni < 5; ++ni) {
    if (ni < NCOL) {
      const float qb = wq_b[(wn * 5 + ni) * 16 + col16];
      float pz = 0.f;
      float po[16];
#pragma unroll
      for (int d = 0; d < 16; ++d) po[d] = 0.f;
#pragma unroll
      for (int mi = 0; mi < 2; ++mi) {
#pragma unroll
        for (int r = 0; r < 4; ++r) {
          const int j = (wm * 2 + mi) * 16 + rbase + r;
          const float ksj = ks_s[j];
          const float4 v0 = *(const float4*)&vt[j * 20];
          const float4 v1 = *(const float4*)&vt[j * 20 + 4];
          const float4 v2 = *(const float4*)&vt[j * 20 + 8];
          const float4 v3 = *(const float4*)&vt[j * 20 + 12];
          const float q   = q_lds[(size_t)j * 132 + (wn * 5 + ni) * 16 + col16] + qb;
          const float e2x = __expf(2.f * q * ksj);
          const float t   = 1.f - 2.f / (e2x + 1.f);
          const float p   = __expf(t);
          pz += p;
          po[0]  += p * v0.x; po[1]  += p * v0.y; po[2]  += p * v0.z; po[3]  += p * v0.w;
          po[4]  += p * v1.x; po[5]  += p * v1.y; po[6]  += p * v1.z; po[7]  += p * v1.w;
          po[8]  += p * v2.x; po[9]  += p * v2.y; po[10] += p * v2.z; po[11] += p * v2.w;
          po[12] += p * v3.x; po[13] += p * v3.y; po[14] += p * v3.z; po[15] += p * v3.w;
        }
      }
      // reduce across lane bits 4,5 (the 4 rbase groups -> this wave's 32 j's)
      pz += __shfl_xor(pz, 16);
      pz += __shfl_xor(pz, 32);
#pragma unroll
      for (int d = 0; d < 16; ++d) {
        po[d] += __shfl_xor(po[d], 16);
        po[d] += __shfl_xor(po[d], 32);
      }
      if (lane < 16) {
        const int n = (wn * 5 + ni) * 16 + lane;
        epiw[n * 18 + 16] = pz;
#pragma unroll
        for (int d = 0; d < 16; ++d) epiw[n * 18 + d] = po[d];
      }
    }
  }
  __syncthreads();
  // coalesced store of [128][17] partial slab (sum of the two wm halves)
  float* pout = part + ((size_t)(b * 32 + jt) * 128) * 17;
  for (int idx = tid; idx < 128 * 17; idx += 256) {
    const int row = idx / 17, c = idx % 17;
    pout[idx] = epi[row * 18 + c] + epi[128 * 18 + row * 18 + c];
  }
}

// -------- finalize: out[b,i,d] = sum_jt O / sum_jt Z ------------------------
__global__ __launch_bounds__(256) void finalize_kernel(const float* __restrict__ part,
                                                       float* __restrict__ out) {
  const int gid = blockIdx.x * 256 + threadIdx.x;   // 0..2047 = (b,i)
  const float* p = part + (size_t)(gid >> 7) * 32 * 128 * 17 + (size_t)(gid & 127) * 17;
  float z = 0.f;
  float o[16];
#pragma unroll
  for (int d = 0; d < 16; ++d) o[d] = 0.f;
  // unroll 4: batch the independent loads (same fp add order per lane)
#pragma unroll 4
  for (int jt = 0; jt < 32; ++jt) {
    const float* pp = p + (size_t)jt * 128 * 17;
    z += pp[16];
#pragma unroll
    for (int d = 0; d < 16; ++d) o[d] += pp[d];
  }
  const float inv = 1.f / z;
  float* dst = out + (size_t)gid * 16;
#pragma unroll
  for (int d = 0; d < 16; ++d) dst[d] = o[d] * inv;
}

// ---------------------------------------------------------------------------
extern "C" void kernel_launch(void* const* d_in, const int* in_sizes, int n_in,
                              void* d_out, int out_size, void* d_ws, size_t ws_size,
                              hipStream_t stream) {
  const float* vec  = (const float*)d_in[0];
  const float* wq_w = (const float*)d_in[1];
  const float* wq_b = (const float*)d_in[2];
  const float* wk_w = (const float*)d_in[3];
  const float* wk_b = (const float*)d_in[4];
  const float* wv_w = (const float*)d_in[5];
  const float* wv_b = (const float*)d_in[6];

  float* ws   = (float*)d_ws;
  uint4* wpk  = (uint4*)(ws + WS_WPK);
  float* part = ws + WS_PART;
  float* out  = (float*)d_out;

  prep1_kernel<<<257, 256, 0, stream>>>(wk_w, wk_b, ws);
  prep2_kernel<<<(NCHUNK * B_UNITS) / 256, 256, 0, stream>>>(wq_w, wv_w, ws, wpk);
  proj_kernel<<<Bn * (Jn / 64), 256, 0, stream>>>(vec, wq_b, wv_b, ws, wpk, part);
  finalize_kernel<<<8, 256, 0, stream>>>(part, out);
}

// Round 2
// 448.138 us; speedup vs baseline: 1.0074x; 1.0020x over previous
//
#include <hip/hip_runtime.h>
#include <hip/hip_bf16.h>
#include <math.h>

#define Bn   16
#define Jn   2048
#define Hn   2048
#define OUTn 128
#define HDn  16

// proj tiling: block M=64 (j), N=160 (128 q + 16 v + 1 ksum + 15 zero), KC=64
// MFMA 32x32x16: N = 5 tiles of 32; K-chunk = 4 ksteps of 16.
#define KC      64
#define NCHUNK  (Hn / KC)          // 32
#define B_UNITS 1280               // 4 ksteps * 5 ntiles * 64 lanes per plane
#define WPK_CHUNK_BYTES (2 * B_UNITS * 16)   // 40960 B per chunk (hi+lo)

// workspace layout (floats)
#define WS_PART1 2048                        // [256][2048] col-sum partials
#define WS_WPK   (WS_PART1 + 256 * 2048)     // packed weights (uint4 region)
#define WS_PART  (WS_WPK + NCHUNK * 2 * B_UNITS * 4)  // [16][32][128][17] attn partials

typedef __attribute__((ext_vector_type(8))) short bf16x8_t;
typedef __attribute__((ext_vector_type(4))) float f32x4_t;
typedef __attribute__((ext_vector_type(16))) float f32x16_t;

typedef __attribute__((address_space(1))) const void gvoid_t;
typedef __attribute__((address_space(3))) void lvoid_t;

__device__ __forceinline__ unsigned short f2bf(float x) {
  unsigned u = __builtin_bit_cast(unsigned, x);
  unsigned r = (u + 0x7fffu + ((u >> 16) & 1u)) >> 16;
  return (unsigned short)r;
}
__device__ __forceinline__ float bf2f(unsigned short h) {
  unsigned u = ((unsigned)h) << 16;
  return __builtin_bit_cast(float, u);
}

// convert 8 consecutive fp32 -> split-bf16 (hi + lo) fragments
__device__ __forceinline__ void cvt8(const float4 u, const float4 v,
                                     bf16x8_t& h, bf16x8_t& l) {
  float x[8] = {u.x, u.y, u.z, u.w, v.x, v.y, v.z, v.w};
#pragma unroll
  for (int i = 0; i < 8; ++i) {
    const unsigned short hi = f2bf(x[i]);
    h[i] = (short)hi;
    l[i] = (short)f2bf(x[i] - bf2f(hi));
  }
}

// -------- prep1: contention-free column-sum partials of wk_w ---------------
__global__ __launch_bounds__(256) void prep1_kernel(const float* __restrict__ wk_w,
                                                    const float* __restrict__ wk_b,
                                                    float* __restrict__ ws) {
  const int blk = blockIdx.x;
  const int tid = threadIdx.x;
  if (blk < 256) {
    const int h0 = blk * 8;
    const int c0 = tid * 8;
    float a[8] = {0.f, 0.f, 0.f, 0.f, 0.f, 0.f, 0.f, 0.f};
#pragma unroll
    for (int h = 0; h < 8; ++h) {
      const float* row = wk_w + (size_t)(h0 + h) * Hn + c0;
      const float4 u = *(const float4*)row;
      const float4 v = *(const float4*)(row + 4);
      a[0] += u.x; a[1] += u.y; a[2] += u.z; a[3] += u.w;
      a[4] += v.x; a[5] += v.y; a[6] += v.z; a[7] += v.w;
    }
    float* dst = ws + WS_PART1 + (size_t)blk * Hn + c0;
    *(float4*)dst       = make_float4(a[0], a[1], a[2], a[3]);
    *(float4*)(dst + 4) = make_float4(a[4], a[5], a[6], a[7]);
  } else {
    __shared__ float red[256];
    float s = 0.f;
    for (int h = tid; h < Hn; h += 256) s += wk_b[h];
    red[tid] = s;
    __syncthreads();
    for (int off = 128; off > 0; off >>= 1) {
      if (tid < off) red[tid] += red[tid + off];
      __syncthreads();
    }
    if (tid == 0) ws[0] = red[0];
  }
}

// -------- prep2: pack weights into split-bf16, 32x32-MFMA-tile stream -------
// Stream per chunk: [plane 2][kstep 4][ntile 5][lane 64] x 16B.
// Lane fragment: col n = nt*32 + (l&31), k = chunk*64 + kstep*16 + (l>>5)*8,
// 8 consecutive k-values of column n (the 32x32x16 B-fragment layout).
__global__ __launch_bounds__(256) void prep2_kernel(const float* __restrict__ wq_w,
                                                    const float* __restrict__ wv_w,
                                                    const float* __restrict__ ws,
                                                    uint4* __restrict__ wpk) {
  const int id = blockIdx.x * 256 + threadIdx.x;     // 0 .. 40959
  const int chunk = id / B_UNITS;
  const int u     = id % B_UNITS;
  const int kstep = u / 320;
  const int r2    = u % 320;
  const int nt    = r2 >> 6;         // 0..4
  const int l     = r2 & 63;
  const int n     = nt * 32 + (l & 31);
  const int k     = chunk * KC + kstep * 16 + (l >> 5) * 8;

  float x[8];
  if (n < OUTn) {
    const float* s = wq_w + (size_t)n * Hn + k;
#pragma unroll
    for (int i = 0; i < 8; ++i) x[i] = s[i];
  } else if (n < OUTn + HDn) {
    const float* s = wv_w + (size_t)(n - OUTn) * Hn + k;
#pragma unroll
    for (int i = 0; i < 8; ++i) x[i] = s[i];
  } else if (n == OUTn + HDn) {
#pragma unroll
    for (int i = 0; i < 8; ++i) x[i] = 0.f;
    const float* p1 = ws + WS_PART1 + k;
#pragma unroll 8
    for (int p = 0; p < 256; ++p) {
      const float4 a = *(const float4*)p1;
      const float4 b = *(const float4*)(p1 + 4);
      x[0] += a.x; x[1] += a.y; x[2] += a.z; x[3] += a.w;
      x[4] += b.x; x[5] += b.y; x[6] += b.z; x[7] += b.w;
      p1 += Hn;
    }
  } else {
#pragma unroll
    for (int i = 0; i < 8; ++i) x[i] = 0.f;
  }

  unsigned short hi[8], lo[8];
#pragma unroll
  for (int i = 0; i < 8; ++i) {
    hi[i] = f2bf(x[i]);
    lo[i] = f2bf(x[i] - bf2f(hi[i]));
  }
  uint4 uh, ul;
  uh.x = (unsigned)hi[0] | ((unsigned)hi[1] << 16);
  uh.y = (unsigned)hi[2] | ((unsigned)hi[3] << 16);
  uh.z = (unsigned)hi[4] | ((unsigned)hi[5] << 16);
  uh.w = (unsigned)hi[6] | ((unsigned)hi[7] << 16);
  ul.x = (unsigned)lo[0] | ((unsigned)lo[1] << 16);
  ul.y = (unsigned)lo[2] | ((unsigned)lo[3] << 16);
  ul.z = (unsigned)lo[4] | ((unsigned)lo[5] << 16);
  ul.w = (unsigned)lo[6] | ((unsigned)lo[7] << 16);
  wpk[(size_t)(chunk * 2 + 0) * B_UNITS + u] = uh;
  wpk[(size_t)(chunk * 2 + 1) * B_UNITS + u] = ul;
}

// -------- proj: 32x32x16-MFMA split-bf16 GEMM, k-split wave pairs -----------
// Why 32x32: halves LDS b128 reads per FLOP. Per CU per chunk:
//   LDS 160 reads x 12cy = 1920 cy;  MFMA 8 waves x 30 x 8.07 = 1937 cy;
//   HBM 32KB = 3048 cy  -> HBM-bound (was LDS-bound at 3840 cy with 16x16).
// Waves: wpair = w>>1 owns 32-row m-tile; whalf = w&1 owns ksteps whalf*2..+1
// (vec still read exactly once; k-partials pair-reduced via LDS at the end).
__global__ __launch_bounds__(256, 2) void proj_kernel(
    const float* __restrict__ vec,
    const float* __restrict__ wq_b,
    const float* __restrict__ wv_b,
    const float* __restrict__ wsc,     // ws[0] = wkb sum
    const uint4* __restrict__ wpk,     // packed split-bf16 weights
    float* __restrict__ part)          // [B][32][128][17] attn partials
{
  __shared__ uint4 Bs[2][2 * B_UNITS];   // 2 x 40 KB double-buffered B

  const int tid   = threadIdx.x;
  const int lane  = tid & 63;
  const int w     = tid >> 6;          // wave 0..3
  const int wpair = w >> 1;            // m-tile (32 rows)
  const int whalf = w & 1;             // k-half (ksteps whalf*2 .. +1)
  const int b     = blockIdx.x >> 5;
  const int jt    = blockIdx.x & 31;
  const int j0    = jt * 64;
  const int col16 = lane & 15;
  const int rbase = (lane >> 4) * 4;

  // A base: row j0 + wpair*32 + (lane&31); k-offset whalf*32 + (lane>>5)*8
  const float* aptr = vec + (size_t)b * Jn * Hn
                    + (size_t)(j0 + wpair * 32 + (lane & 31)) * Hn
                    + whalf * 32 + (lane >> 5) * 8;

  f32x16_t acc[5];
#pragma unroll
  for (int ni = 0; ni < 5; ++ni)
#pragma unroll
    for (int rg = 0; rg < 16; ++rg) acc[ni][rg] = 0.f;

#define STAGE_B(ch_, buf_)                                                    \
  do {                                                                        \
    const char* gb_ = (const char*)wpk + (size_t)(ch_) * WPK_CHUNK_BYTES +    \
                      (size_t)lane * 16;                                      \
    uint4* bd_ = &Bs[buf_][0];                                                \
    _Pragma("unroll")                                                         \
    for (int i_ = 0; i_ < 10; ++i_) {                                         \
      const int q_ = w + i_ * 4;                                              \
      __builtin_amdgcn_global_load_lds((gvoid_t*)(gb_ + q_ * 1024),           \
                                       (lvoid_t*)(bd_ + q_ * 64), 16, 0, 0);  \
    }                                                                         \
  } while (0)

// one K-chunk: stage B(ch+1) -> other buffer, prefetch A(ch+1) -> regs,
// convert current A regs, 30 MFMAs (32x32x16) from this wave's 2 ksteps,
// counted wait (B drained, A still in flight) + 1 barrier.
#define CHUNK_BODY(ch_, buf_, u0, u1, u2, u3, v0_, v1_, v2_, v3_)             \
  do {                                                                        \
    if ((ch_) + 1 < NCHUNK) { STAGE_B((ch_) + 1, (buf_) ^ 1); }               \
    asm volatile("" ::: "memory"); /* order: B stages before A prefetch */    \
    if ((ch_) + 1 < NCHUNK) {                                                 \
      const float* ap_ = aptr + (size_t)((ch_) + 1) * KC;                     \
      v0_ = *(const float4*)(ap_);                                            \
      v1_ = *(const float4*)(ap_ + 4);                                        \
      v2_ = *(const float4*)(ap_ + 16);                                       \
      v3_ = *(const float4*)(ap_ + 20);                                       \
    }                                                                         \
    bf16x8_t ah0_, al0_, ah1_, al1_;                                          \
    cvt8(u0, u1, ah0_, al0_);                                                 \
    cvt8(u2, u3, ah1_, al1_);                                                 \
    const bf16x8_t* B8_ = (const bf16x8_t*)&Bs[buf_][0];                      \
    _Pragma("unroll")                                                         \
    for (int kl_ = 0; kl_ < 2; ++kl_) {                                       \
      const bf16x8_t ah_ = kl_ ? ah1_ : ah0_;                                 \
      const bf16x8_t al_ = kl_ ? al1_ : al0_;                                 \
      _Pragma("unroll")                                                       \
      for (int ni_ = 0; ni_ < 5; ++ni_) {                                     \
        const int idx_ = ((whalf * 2 + kl_) * 5 + ni_) * 64 + lane;           \
        const bf16x8_t bh_ = B8_[idx_];                                       \
        const bf16x8_t bl_ = B8_[B_UNITS + idx_];                             \
        acc[ni_] = __builtin_amdgcn_mfma_f32_32x32x16_bf16(ah_, bh_, acc[ni_], 0, 0, 0); \
        acc[ni_] = __builtin_amdgcn_mfma_f32_32x32x16_bf16(ah_, bl_, acc[ni_], 0, 0, 0); \
        acc[ni_] = __builtin_amdgcn_mfma_f32_32x32x16_bf16(al_, bh_, acc[ni_], 0, 0, 0); \
      }                                                                       \
    }                                                                         \
    asm volatile("s_waitcnt vmcnt(4)" ::: "memory"); /* B staged; A flying */ \
    __builtin_amdgcn_s_barrier();                                             \
  } while (0)

  // prologue: stage B(0), load A(0)
  STAGE_B(0, 0);
  asm volatile("" ::: "memory");
  float4 c0 = *(const float4*)(aptr);
  float4 c1 = *(const float4*)(aptr + 4);
  float4 c2 = *(const float4*)(aptr + 16);
  float4 c3 = *(const float4*)(aptr + 20);
  asm volatile("s_waitcnt vmcnt(4)" ::: "memory");
  __builtin_amdgcn_s_barrier();

  float4 n0, n1, n2, n3;
  for (int ch = 0; ch < NCHUNK; ch += 2) {
    CHUNK_BODY(ch,     0, c0, c1, c2, c3, n0, n1, n2, n3);
    CHUNK_BODY(ch + 1, 1, n0, n1, n2, n3, c0, c1, c2, c3);
  }
#undef CHUNK_BODY
#undef STAGE_B

  // ==== pairwise k-reduction, then spill to the old epilogue layout ====
  // 32x32 C/D layout: col = lane&31, row = (reg&3) + 8*(reg>>2) + 4*(lane>>5).
  __syncthreads();
  float* lds_f = (float*)Bs;
  float* redf  = lds_f + 10240;        // bytes [40960,81920): 2 x 5120 floats
  if (whalf == 1) {
#pragma unroll
    for (int ni = 0; ni < 5; ++ni)
#pragma unroll
      for (int rg = 0; rg < 16; ++rg)
        redf[wpair * 5120 + (ni * 16 + rg) * 64 + lane] = acc[ni][rg];
  }
  __syncthreads();

  const float wkb = wsc[0];
  float* q_lds = lds_f;                // [64][132] floats
  float* ks_s  = q_lds + 64 * 132;     // [64]
  float* vt    = ks_s + 64;            // [64][20], rows 16B-aligned
  float* epi   = vt + 64 * 20;         // [2][128][18] (overlaps dead redf: ok,
                                       // written only after next barrier)
  if (whalf == 0) {
#pragma unroll
    for (int ni = 0; ni < 5; ++ni)
#pragma unroll
      for (int rg = 0; rg < 16; ++rg)
        acc[ni][rg] += redf[wpair * 5120 + (ni * 16 + rg) * 64 + lane];
    const int cc = lane & 31;
    const int jh = 4 * (lane >> 5);
#pragma unroll
    for (int nt = 0; nt < 4; ++nt)
#pragma unroll
      for (int rg = 0; rg < 16; ++rg) {
        const int j = wpair * 32 + (rg & 3) + 8 * (rg >> 2) + jh;
        q_lds[(size_t)j * 132 + nt * 32 + cc] = acc[nt][rg];
      }
    if (cc < 16) {
      const float vb_ = wv_b[cc];
#pragma unroll
      for (int rg = 0; rg < 16; ++rg) {
        const int j = wpair * 32 + (rg & 3) + 8 * (rg >> 2) + jh;
        vt[j * 20 + cc] = acc[4][rg] + vb_;     // v columns: n = 128 + cc
      }
    } else if (cc == 16) {
#pragma unroll
      for (int rg = 0; rg < 16; ++rg) {
        const int j = wpair * 32 + (rg & 3) + 8 * (rg >> 2) + jh;
        ks_s[j] = acc[4][rg] + wkb;             // ksum column: n = 144
      }
    }
  }
  __syncthreads();

  // old softmax epilogue verbatim (wm/wn wave roles), q sourced from q_lds
  const int wm   = w >> 1;
  const int wn   = w & 1;
  const int NCOL = wn ? 3 : 5;           // q columns this wave owns (uniform)
  float* epiw = epi + wm * 128 * 18;     // this wave's disjoint slab

#pragma unroll 5
  for (int ni = 0; ni < 5; ++ni) {
    if (ni < NCOL) {
      const float qb = wq_b[(wn * 5 + ni) * 16 + col16];
      float pz = 0.f;
      float po[16];
#pragma unroll
      for (int d = 0; d < 16; ++d) po[d] = 0.f;
#pragma unroll
      for (int mi = 0; mi < 2; ++mi) {
#pragma unroll
        for (int r = 0; r < 4; ++r) {
          const int j = (wm * 2 + mi) * 16 + rbase + r;
          const float ksj = ks_s[j];
          const float4 v0 = *(const float4*)&vt[j * 20];
          const float4 v1 = *(const float4*)&vt[j * 20 + 4];
          const float4 v2 = *(const float4*)&vt[j * 20 + 8];
          const float4 v3 = *(const float4*)&vt[j * 20 + 12];
          const float q   = q_lds[(size_t)j * 132 + (wn * 5 + ni) * 16 + col16] + qb;
          const float e2x = __expf(2.f * q * ksj);
          const float t   = 1.f - 2.f / (e2x + 1.f);
          const float p   = __expf(t);
          pz += p;
          po[0]  += p * v0.x; po[1]  += p * v0.y; po[2]  += p * v0.z; po[3]  += p * v0.w;
          po[4]  += p * v1.x; po[5]  += p * v1.y; po[6]  += p * v1.z; po[7]  += p * v1.w;
          po[8]  += p * v2.x; po[9]  += p * v2.y; po[10] += p * v2.z; po[11] += p * v2.w;
          po[12] += p * v3.x; po[13] += p * v3.y; po[14] += p * v3.z; po[15] += p * v3.w;
        }
      }
      // reduce across lane bits 4,5 (the 4 rbase groups -> this wave's 32 j's)
      pz += __shfl_xor(pz, 16);
      pz += __shfl_xor(pz, 32);
#pragma unroll
      for (int d = 0; d < 16; ++d) {
        po[d] += __shfl_xor(po[d], 16);
        po[d] += __shfl_xor(po[d], 32);
      }
      if (lane < 16) {
        const int n = (wn * 5 + ni) * 16 + lane;
        epiw[n * 18 + 16] = pz;
#pragma unroll
        for (int d = 0; d < 16; ++d) epiw[n * 18 + d] = po[d];
      }
    }
  }
  __syncthreads();
  // coalesced store of [128][17] partial slab (sum of the two wm halves)
  float* pout = part + ((size_t)(b * 32 + jt) * 128) * 17;
  for (int idx = tid; idx < 128 * 17; idx += 256) {
    const int row = idx / 17, c = idx % 17;
    pout[idx] = epi[row * 18 + c] + epi[128 * 18 + row * 18 + c];
  }
}

// -------- finalize: out[b,i,d] = sum_jt O / sum_jt Z ------------------------
__global__ __launch_bounds__(256) void finalize_kernel(const float* __restrict__ part,
                                                       float* __restrict__ out) {
  const int gid = blockIdx.x * 256 + threadIdx.x;   // 0..2047 = (b,i)
  const float* p = part + (size_t)(gid >> 7) * 32 * 128 * 17 + (size_t)(gid & 127) * 17;
  float z = 0.f;
  float o[16];
#pragma unroll
  for (int d = 0; d < 16; ++d) o[d] = 0.f;
#pragma unroll 4
  for (int jt = 0; jt < 32; ++jt) {
    const float* pp = p + (size_t)jt * 128 * 17;
    z += pp[16];
#pragma unroll
    for (int d = 0; d < 16; ++d) o[d] += pp[d];
  }
  const float inv = 1.f / z;
  float* dst = out + (size_t)gid * 16;
#pragma unroll
  for (int d = 0; d < 16; ++d) dst[d] = o[d] * inv;
}

// ---------------------------------------------------------------------------
extern "C" void kernel_launch(void* const* d_in, const int* in_sizes, int n_in,
                              void* d_out, int out_size, void* d_ws, size_t ws_size,
                              hipStream_t stream) {
  const float* vec  = (const float*)d_in[0];
  const float* wq_w = (const float*)d_in[1];
  const float* wq_b = (const float*)d_in[2];
  const float* wk_w = (const float*)d_in[3];
  const float* wk_b = (const float*)d_in[4];
  const float* wv_w = (const float*)d_in[5];
  const float* wv_b = (const float*)d_in[6];

  float* ws   = (float*)d_ws;
  uint4* wpk  = (uint4*)(ws + WS_WPK);
  float* part = ws + WS_PART;
  float* out  = (float*)d_out;

  prep1_kernel<<<257, 256, 0, stream>>>(wk_w, wk_b, ws);
  prep2_kernel<<<(NCHUNK * B_UNITS) / 256, 256, 0, stream>>>(wq_w, wv_w, ws, wpk);
  proj_kernel<<<Bn * (Jn / 64), 256, 0, stream>>>(vec, wq_b, wv_b, ws, wpk, part);
  finalize_kernel<<<8, 256, 0, stream>>>(part, out);
}